// Round 4
// baseline (720.299 us; speedup 1.0000x reference)
//
#include <hip/hip_runtime.h>
#include <stdint.h>

typedef uint16_t u16;
typedef __bf16 bf16x8 __attribute__((ext_vector_type(8)));
typedef float f32x4 __attribute__((ext_vector_type(4)));

#define NCHUNK 50            // 250 tiles / 5 per chunk
#define TILES_PER_CHUNK 5
#define NPART  (2 * NCHUNK)  // 2 col-half waves write separate partials
#define NROWS  4096          // 2L

__device__ __forceinline__ u16 f2b(float x) {
    uint32_t u = __float_as_uint(x);
    u += 0x7FFF + ((u >> 16) & 1);
    return (u16)(u >> 16);
}
__device__ __forceinline__ float b2f(u16 h) {
    return __uint_as_float(((uint32_t)h) << 16);
}

// async global->LDS, 16B per lane. LDS side must be wave-uniform base + lane*16.
__device__ __forceinline__ void cp16(const void* g, void* l) {
    __builtin_amdgcn_global_load_lds(
        (const __attribute__((address_space(1))) uint32_t*)g,
        (__attribute__((address_space(3))) uint32_t*)l, 16, 0, 0);
}

__device__ __forceinline__ float fast_tanh(float x) {
    x = fminf(15.f, fmaxf(-15.f, x));
    float e = __expf(2.f * x);
    return (e - 1.f) / (e + 1.f);
}

// fp32 -> bf16 (RNE), 4 elems/thread grid-stride
__global__ void k_convert(const float* __restrict__ src, u16* __restrict__ dst, int n) {
    int i = (blockIdx.x * blockDim.x + threadIdx.x) * 4;
    int stride = gridDim.x * blockDim.x * 4;
    for (; i < n; i += stride) {
        float4 v = *(const float4*)(src + i);
        u16 o[4] = {f2b(v.x), f2b(v.y), f2b(v.z), f2b(v.w)};
        *(uint64_t*)(dst + i) = *(const uint64_t*)o;
    }
}

// span gathers -> bf16 context/phrase matrices [2048][1024]
__global__ void k_gather(const float* __restrict__ hidden, const int* __restrict__ begins,
                         const int* __restrict__ ends, const int* __restrict__ bids,
                         u16* __restrict__ ctx, u16* __restrict__ phr) {
    int l = blockIdx.x;
    int b = begins[l], e = ends[l], bd = bids[l];
    const float* h_bm1 = hidden + ((size_t)(b - 1) * 32 + bd) * 1024;
    const float* h_e   = hidden + ((size_t)e * 32 + bd) * 1024;
    const float* h_b   = hidden + ((size_t)b * 32 + bd) * 1024;
    const float* h_em1 = hidden + ((size_t)(e - 1) * 32 + bd) * 1024;
    for (int d = threadIdx.x; d < 1024; d += blockDim.x) {
        float c = (d < 512) ? h_bm1[d] : h_e[d];
        float p = 0.5f * (h_b[d] + h_em1[d]);
        ctx[(size_t)l * 1024 + d] = f2b(c);
        phr[(size_t)l * 1024 + d] = f2b(p);
    }
}

// feats[z*2048 + m][n] = tanh(A[m] . W[n] + bias[n]),  A:[2048][1024] W:[512][1024]
__global__ __launch_bounds__(256) void k_feats(const u16* __restrict__ ctx, const u16* __restrict__ phr,
        const u16* __restrict__ Wc, const u16* __restrict__ Wp,
        const float* __restrict__ bc, const float* __restrict__ bp,
        u16* __restrict__ feats) {
    __shared__ u16 lA[64 * 32];
    __shared__ u16 lB[64 * 32];
    int z = blockIdx.z;
    const u16* A = z ? phr : ctx;
    const u16* W = z ? Wp : Wc;
    const float* bias = z ? bp : bc;
    int m0 = blockIdx.x * 64;
    int n0 = blockIdx.y * 64;
    int t = threadIdx.x;
    int lane = t & 63, w = t >> 6;
    int lrow = lane & 15, lq = lane >> 4;
    f32x4 zero = {0.f, 0.f, 0.f, 0.f};
    f32x4 acc[4];
    for (int i = 0; i < 4; i++) acc[i] = zero;
    int row = t >> 2, kseg = (t & 3) * 8;
    for (int kt = 0; kt < 32; kt++) {
        int k0 = kt * 32;
        __syncthreads();
        cp16(&A[(size_t)(m0 + row) * 1024 + k0 + kseg], &lA[t * 8]);
        cp16(&W[(size_t)(n0 + row) * 1024 + k0 + kseg], &lB[t * 8]);
        __syncthreads();
        bf16x8 af = *(bf16x8*)&lA[(w * 16 + lrow) * 32 + lq * 8];
        for (int ns = 0; ns < 4; ns++) {
            bf16x8 bfr = *(bf16x8*)&lB[(ns * 16 + lrow) * 32 + lq * 8];
            acc[ns] = __builtin_amdgcn_mfma_f32_16x16x32_bf16(af, bfr, acc[ns], 0, 0, 0);
        }
    }
    int zbase = z * 2048;
    for (int ns = 0; ns < 4; ns++) {
        int col = n0 + ns * 16 + lrow;
        float bv = bias[col];
        for (int r = 0; r < 4; r++) {
            int orow = zbase + m0 + w * 16 + lq * 4 + r;
            feats[(size_t)orow * 512 + col] = f2b(fast_tanh(acc[ns][r] + bv));
        }
    }
}

// big GEMM + row sum-of-exp: feats[4096][512] @ Wo_b[32000][512]^T
// grid (32 m-tiles, 50 chunks of 5 col-tiles); block 256 = 4 waves in 2x2,
// wave tile 64x64 (acc[4][4]). A read direct from global (L2-hot), B via LDS.
// No max-tracking: |logit| <= 512/sqrt(512) = 22.6, exp never overflows.
// NOTE: waves w and w^2 share rows with different col halves -> separate
// partial slots per (w>>1), merged in k_final.
__global__ __launch_bounds__(256, 3) void k_lse(const u16* __restrict__ feats,
        const u16* __restrict__ Wo, const float* __restrict__ bo, float* __restrict__ ps) {
    __shared__ u16 lB[128 * 32];
    int m0 = blockIdx.x * 128;
    int chunk = blockIdx.y;
    int t = threadIdx.x;
    int lane = t & 63, w = t >> 6;
    int lrow = lane & 15, lq = lane >> 4;
    int wrow = (w & 1) * 64, wcol = (w >> 1) * 64;

    const u16* Arow[4];
    for (int mi = 0; mi < 4; mi++)
        Arow[mi] = feats + (size_t)(m0 + wrow + mi * 16 + lrow) * 512 + lq * 8;

    // staging: 512 16B segs, 2 per thread; seg s -> Wo row n0+(s>>2), k (s&3)*8, LDS byte s*16
    int srow1 = t >> 2, sk1 = (t & 3) * 8;
    int s2 = t + 256;
    int srow2 = s2 >> 2, sk2 = (s2 & 3) * 8;

    float s_state[4][4];
    for (int mi = 0; mi < 4; mi++)
        for (int r = 0; r < 4; r++) s_state[mi][r] = 0.f;
    f32x4 zero = {0.f, 0.f, 0.f, 0.f};

    for (int tile = 0; tile < TILES_PER_CHUNK; tile++) {
        int n0 = (chunk * TILES_PER_CHUNK + tile) * 128;
        f32x4 acc[4][4];
        for (int mi = 0; mi < 4; mi++)
            for (int ni = 0; ni < 4; ni++) acc[mi][ni] = zero;
        for (int kt = 0; kt < 16; kt++) {
            int k0 = kt * 32;
            __syncthreads();
            bf16x8 af[4];
            for (int mi = 0; mi < 4; mi++) af[mi] = *(const bf16x8*)(Arow[mi] + k0);
            cp16(&Wo[(size_t)(n0 + srow1) * 512 + k0 + sk1], &lB[t * 8]);
            cp16(&Wo[(size_t)(n0 + srow2) * 512 + k0 + sk2], &lB[(size_t)s2 * 8]);
            __syncthreads();
            for (int ni = 0; ni < 4; ni++) {
                bf16x8 bfr = *(bf16x8*)&lB[(wcol + ni * 16 + lrow) * 32 + lq * 8];
                for (int mi = 0; mi < 4; mi++)
                    acc[mi][ni] = __builtin_amdgcn_mfma_f32_16x16x32_bf16(af[mi], bfr, acc[mi][ni], 0, 0, 0);
            }
        }
        // epilogue: sum exp(logit + bo) into per-row state (no max needed)
        for (int ni = 0; ni < 4; ni++) {
            float bov = bo[n0 + wcol + ni * 16 + lrow];
            for (int mi = 0; mi < 4; mi++)
                for (int r = 0; r < 4; r++)
                    s_state[mi][r] += __expf(acc[mi][ni][r] + bov);
        }
    }
    // merge cols across the 16 lanes of each quad-group (xor 1,2,4,8 stays in-group)
    for (int mi = 0; mi < 4; mi++)
    for (int r = 0; r < 4; r++) {
        float s = s_state[mi][r];
        for (int off = 1; off < 16; off <<= 1) s += __shfl_xor(s, off);
        if (lrow == 0) {
            int row = m0 + wrow + mi * 16 + lq * 4 + r;
            ps[row * NPART + chunk * 2 + (w >> 1)] = s;
        }
    }
}

// tag logits: one wave per (row, k): dot(feats[row], Wo[tag]) + bo[tag]
__global__ void k_taglog(const u16* __restrict__ feats, const u16* __restrict__ Wo,
        const float* __restrict__ bo, const int* __restrict__ tags, float* __restrict__ tlog) {
    int gw = blockIdx.x * 4 + (threadIdx.x >> 6);
    int lane = threadIdx.x & 63;
    int i = gw >> 1, k = gw & 1;
    int tg = tags[(i & 2047) * 2 + k];
    union { int4 v; u16 h[8]; } fa, wa;
    fa.v = *(const int4*)(feats + (size_t)i * 512 + lane * 8);
    wa.v = *(const int4*)(Wo + (size_t)tg * 512 + lane * 8);
    float s = 0.f;
    for (int j = 0; j < 8; j++) s += b2f(fa.h[j]) * b2f(wa.h[j]);
    for (int off = 32; off >= 1; off >>= 1) s += __shfl_down(s, off);
    if (lane == 0) tlog[i * 2 + k] = s + bo[tg];
}

// lse = log(sum of chunk partials) + loss reduction
__global__ void k_final(const float* __restrict__ ps,
        const float* __restrict__ tlog, const int* __restrict__ tags,
        const float* __restrict__ dp, float* __restrict__ out) {
    __shared__ float red[256];
    float acc = 0.f;
    for (int i = threadIdx.x; i < NROWS; i += 256) {
        float S = 0.f;
        for (int j = 0; j < NPART; j++) S += ps[i * NPART + j];
        float lse = logf(S);
        float num = 0.f, den = 0.f;
        for (int k = 0; k < 2; k++) {
            int tg = tags[(i & 2047) * 2 + k];
            float r = 1.0f - dp[tg];
            num += r * (lse - tlog[i * 2 + k]);
            den += r;
        }
        acc += num / den;
    }
    red[threadIdx.x] = acc;
    __syncthreads();
    for (int s = 128; s > 0; s >>= 1) {
        if (threadIdx.x < s) red[threadIdx.x] += red[threadIdx.x + s];
        __syncthreads();
    }
    if (threadIdx.x == 0) out[0] = red[0] / (4096.0f + 1e-5f);
}

extern "C" void kernel_launch(void* const* d_in, const int* in_sizes, int n_in,
                              void* d_out, int out_size, void* d_ws, size_t ws_size,
                              hipStream_t stream) {
    const float* hidden = (const float*)d_in[0];
    const float* Wc     = (const float*)d_in[1];
    const float* bc     = (const float*)d_in[2];
    const float* Wp     = (const float*)d_in[3];
    const float* bp     = (const float*)d_in[4];
    const float* Wo     = (const float*)d_in[5];
    const float* bo     = (const float*)d_in[6];
    const float* dp     = (const float*)d_in[7];
    const int* begins   = (const int*)d_in[8];
    const int* ends     = (const int*)d_in[9];
    const int* bids     = (const int*)d_in[10];
    const int* tags     = (const int*)d_in[11];
    float* out = (float*)d_out;

    // workspace carve (all 16B-aligned)
    u16* Wo_b    = (u16*)d_ws;
    u16* Wc_b    = Wo_b + 16384000;      // 32000*512
    u16* Wp_b    = Wc_b + 524288;        // 512*1024
    u16* ctx_b   = Wp_b + 524288;
    u16* phr_b   = ctx_b + 2097152;      // 2048*1024
    u16* feats_b = phr_b + 2097152;      // 4096*512
    // ps/tlog alias the ctx region (dead after k_feats; in-stream order safe)
    float* ps    = (float*)ctx_b;                 // 4096*100*4 = 1.6MB < 4MB
    float* tlog  = ps + NROWS * NPART;            // 8192

    k_convert<<<2048, 256, 0, stream>>>(Wo, Wo_b, 16384000);
    k_convert<<<256, 256, 0, stream>>>(Wc, Wc_b, 524288);
    k_convert<<<256, 256, 0, stream>>>(Wp, Wp_b, 524288);
    k_gather<<<2048, 256, 0, stream>>>(hidden, begins, ends, bids, ctx_b, phr_b);
    k_feats<<<dim3(32, 8, 2), 256, 0, stream>>>(ctx_b, phr_b, Wc_b, Wp_b, bc, bp, feats_b);
    k_lse<<<dim3(32, NCHUNK), 256, 0, stream>>>(feats_b, Wo_b, bo, ps);
    k_taglog<<<2048, 256, 0, stream>>>(feats_b, Wo_b, bo, tags, tlog);
    k_final<<<1, 256, 0, stream>>>(ps, tlog, tags, dp, out);
}

// Round 6
// 472.205 us; speedup vs baseline: 1.5254x; 1.5254x over previous
//
#include <hip/hip_runtime.h>
#include <stdint.h>

typedef uint16_t u16;
typedef __bf16 bf16x8 __attribute__((ext_vector_type(8)));
typedef float f32x4 __attribute__((ext_vector_type(4)));

#define NCHUNK 50            // 250 tiles / 5 per chunk
#define TILES_PER_CHUNK 5
#define NPART  (2 * NCHUNK)  // 2 col-half waves write separate partials
#define NROWS  4096          // 2L

__device__ __forceinline__ u16 f2b(float x) {
    uint32_t u = __float_as_uint(x);
    u += 0x7FFF + ((u >> 16) & 1);
    return (u16)(u >> 16);
}
__device__ __forceinline__ float b2f(u16 h) {
    return __uint_as_float(((uint32_t)h) << 16);
}

// async global->LDS, 16B per lane. LDS side must be wave-uniform base + lane*16.
__device__ __forceinline__ void cp16(const void* g, void* l) {
    __builtin_amdgcn_global_load_lds(
        (const __attribute__((address_space(1))) uint32_t*)g,
        (__attribute__((address_space(3))) uint32_t*)l, 16, 0, 0);
}

__device__ __forceinline__ float fast_tanh(float x) {
    x = fminf(15.f, fmaxf(-15.f, x));
    float e = __expf(2.f * x);
    return (e - 1.f) / (e + 1.f);
}

// fp32 -> bf16 (RNE), 4 elems/thread grid-stride
__global__ void k_convert(const float* __restrict__ src, u16* __restrict__ dst, int n) {
    int i = (blockIdx.x * blockDim.x + threadIdx.x) * 4;
    int stride = gridDim.x * blockDim.x * 4;
    for (; i < n; i += stride) {
        float4 v = *(const float4*)(src + i);
        u16 o[4] = {f2b(v.x), f2b(v.y), f2b(v.z), f2b(v.w)};
        *(uint64_t*)(dst + i) = *(const uint64_t*)o;
    }
}

// span gathers -> bf16 context/phrase matrices [2048][1024]
__global__ void k_gather(const float* __restrict__ hidden, const int* __restrict__ begins,
                         const int* __restrict__ ends, const int* __restrict__ bids,
                         u16* __restrict__ ctx, u16* __restrict__ phr) {
    int l = blockIdx.x;
    int b = begins[l], e = ends[l], bd = bids[l];
    const float* h_bm1 = hidden + ((size_t)(b - 1) * 32 + bd) * 1024;
    const float* h_e   = hidden + ((size_t)e * 32 + bd) * 1024;
    const float* h_b   = hidden + ((size_t)b * 32 + bd) * 1024;
    const float* h_em1 = hidden + ((size_t)(e - 1) * 32 + bd) * 1024;
    for (int d = threadIdx.x; d < 1024; d += blockDim.x) {
        float c = (d < 512) ? h_bm1[d] : h_e[d];
        float p = 0.5f * (h_b[d] + h_em1[d]);
        ctx[(size_t)l * 1024 + d] = f2b(c);
        phr[(size_t)l * 1024 + d] = f2b(p);
    }
}

// feats[z*2048 + m][n] = tanh(A[m] . W[n] + bias[n]),  A:[2048][1024] W:[512][1024]
__global__ __launch_bounds__(256) void k_feats(const u16* __restrict__ ctx, const u16* __restrict__ phr,
        const u16* __restrict__ Wc, const u16* __restrict__ Wp,
        const float* __restrict__ bc, const float* __restrict__ bp,
        u16* __restrict__ feats) {
    __shared__ u16 lA[64 * 32];
    __shared__ u16 lB[64 * 32];
    int z = blockIdx.z;
    const u16* A = z ? phr : ctx;
    const u16* W = z ? Wp : Wc;
    const float* bias = z ? bp : bc;
    int m0 = blockIdx.x * 64;
    int n0 = blockIdx.y * 64;
    int t = threadIdx.x;
    int lane = t & 63, w = t >> 6;
    int lrow = lane & 15, lq = lane >> 4;
    f32x4 zero = {0.f, 0.f, 0.f, 0.f};
    f32x4 acc[4];
    for (int i = 0; i < 4; i++) acc[i] = zero;
    int row = t >> 2, kseg = (t & 3) * 8;
    for (int kt = 0; kt < 32; kt++) {
        int k0 = kt * 32;
        __syncthreads();
        cp16(&A[(size_t)(m0 + row) * 1024 + k0 + kseg], &lA[t * 8]);
        cp16(&W[(size_t)(n0 + row) * 1024 + k0 + kseg], &lB[t * 8]);
        __syncthreads();
        bf16x8 af = *(bf16x8*)&lA[(w * 16 + lrow) * 32 + lq * 8];
        for (int ns = 0; ns < 4; ns++) {
            bf16x8 bfr = *(bf16x8*)&lB[(ns * 16 + lrow) * 32 + lq * 8];
            acc[ns] = __builtin_amdgcn_mfma_f32_16x16x32_bf16(af, bfr, acc[ns], 0, 0, 0);
        }
    }
    int zbase = z * 2048;
    for (int ns = 0; ns < 4; ns++) {
        int col = n0 + ns * 16 + lrow;
        float bv = bias[col];
        for (int r = 0; r < 4; r++) {
            int orow = zbase + m0 + w * 16 + lq * 4 + r;
            feats[(size_t)orow * 512 + col] = f2b(fast_tanh(acc[ns][r] + bv));
        }
    }
}

// big GEMM + row sum-of-exp: feats[4096][512] @ Wo_b[32000][512]^T
// grid (32 m-tiles, 50 chunks of 5 col-tiles); block 256 = 4 waves in 2x2,
// wave tile 64x64 (acc[4][4]). BOTH A and B staged via LDS.
// 128x32 tile = 512 16B segs -> TWO cp16 per thread per matrix (R5 bug: one).
// No max-tracking: |logit| <= 512/sqrt(512) = 22.6, exp never overflows.
// Waves w and w^2 share rows with different col halves -> separate partial
// slots indexed by (w>>1), merged in k_final.
__global__ __launch_bounds__(256) void k_lse(const u16* __restrict__ feats,
        const u16* __restrict__ Wo, const float* __restrict__ bo, float* __restrict__ ps) {
    __shared__ u16 lA[128 * 32];
    __shared__ u16 lB[128 * 32];
    int m0 = blockIdx.x * 128;
    int chunk = blockIdx.y;
    int t = threadIdx.x;
    int lane = t & 63, w = t >> 6;
    int lrow = lane & 15, lq = lane >> 4;
    int wrow = (w & 1) * 64, wcol = (w >> 1) * 64;

    // staging: 512 16B segs per matrix, 2 per thread (segs t and t+256)
    // seg s -> row s>>2, k (s&3)*8, LDS byte s*16 (lane-contiguous per wave)
    int srow1 = t >> 2, sk1 = (t & 3) * 8;
    int s2 = t + 256;
    int srow2 = s2 >> 2, sk2 = (s2 & 3) * 8;

    float s_state[4][4];
    for (int mi = 0; mi < 4; mi++)
        for (int r = 0; r < 4; r++) s_state[mi][r] = 0.f;
    f32x4 zero = {0.f, 0.f, 0.f, 0.f};

    for (int tile = 0; tile < TILES_PER_CHUNK; tile++) {
        int n0 = (chunk * TILES_PER_CHUNK + tile) * 128;
        f32x4 acc[4][4];
        for (int mi = 0; mi < 4; mi++)
            for (int ni = 0; ni < 4; ni++) acc[mi][ni] = zero;
        for (int kt = 0; kt < 16; kt++) {
            int k0 = kt * 32;
            __syncthreads();
            cp16(&feats[(size_t)(m0 + srow1) * 512 + k0 + sk1], &lA[t * 8]);
            cp16(&feats[(size_t)(m0 + srow2) * 512 + k0 + sk2], &lA[(size_t)s2 * 8]);
            cp16(&Wo[(size_t)(n0 + srow1) * 512 + k0 + sk1], &lB[t * 8]);
            cp16(&Wo[(size_t)(n0 + srow2) * 512 + k0 + sk2], &lB[(size_t)s2 * 8]);
            __syncthreads();
            bf16x8 af[4];
            for (int mi = 0; mi < 4; mi++)
                af[mi] = *(bf16x8*)&lA[(wrow + mi * 16 + lrow) * 32 + lq * 8];
            for (int ni = 0; ni < 4; ni++) {
                bf16x8 bfr = *(bf16x8*)&lB[(wcol + ni * 16 + lrow) * 32 + lq * 8];
                for (int mi = 0; mi < 4; mi++)
                    acc[mi][ni] = __builtin_amdgcn_mfma_f32_16x16x32_bf16(af[mi], bfr, acc[mi][ni], 0, 0, 0);
            }
        }
        // epilogue: sum exp(logit + bo) into per-row state (no max needed)
        for (int ni = 0; ni < 4; ni++) {
            float bov = bo[n0 + wcol + ni * 16 + lrow];
            for (int mi = 0; mi < 4; mi++)
                for (int r = 0; r < 4; r++)
                    s_state[mi][r] += __expf(acc[mi][ni][r] + bov);
        }
    }
    // merge cols across the 16 lanes of each quad-group (xor 1,2,4,8 stays in-group)
    for (int mi = 0; mi < 4; mi++)
    for (int r = 0; r < 4; r++) {
        float s = s_state[mi][r];
        for (int off = 1; off < 16; off <<= 1) s += __shfl_xor(s, off);
        if (lrow == 0) {
            int row = m0 + wrow + mi * 16 + lq * 4 + r;
            ps[row * NPART + chunk * 2 + (w >> 1)] = s;
        }
    }
}

// tag logits: one wave per (row, k): dot(feats[row], Wo[tag]) + bo[tag]
__global__ void k_taglog(const u16* __restrict__ feats, const u16* __restrict__ Wo,
        const float* __restrict__ bo, const int* __restrict__ tags, float* __restrict__ tlog) {
    int gw = blockIdx.x * 4 + (threadIdx.x >> 6);
    int lane = threadIdx.x & 63;
    int i = gw >> 1, k = gw & 1;
    int tg = tags[(i & 2047) * 2 + k];
    union { int4 v; u16 h[8]; } fa, wa;
    fa.v = *(const int4*)(feats + (size_t)i * 512 + lane * 8);
    wa.v = *(const int4*)(Wo + (size_t)tg * 512 + lane * 8);
    float s = 0.f;
    for (int j = 0; j < 8; j++) s += b2f(fa.h[j]) * b2f(wa.h[j]);
    for (int off = 32; off >= 1; off >>= 1) s += __shfl_down(s, off);
    if (lane == 0) tlog[i * 2 + k] = s + bo[tg];
}

// lse = log(sum of chunk partials) + loss reduction
__global__ void k_final(const float* __restrict__ ps,
        const float* __restrict__ tlog, const int* __restrict__ tags,
        const float* __restrict__ dp, float* __restrict__ out) {
    __shared__ float red[256];
    float acc = 0.f;
    for (int i = threadIdx.x; i < NROWS; i += 256) {
        float S = 0.f;
        for (int j = 0; j < NPART; j++) S += ps[i * NPART + j];
        float lse = logf(S);
        float num = 0.f, den = 0.f;
        for (int k = 0; k < 2; k++) {
            int tg = tags[(i & 2047) * 2 + k];
            float r = 1.0f - dp[tg];
            num += r * (lse - tlog[i * 2 + k]);
            den += r;
        }
        acc += num / den;
    }
    red[threadIdx.x] = acc;
    __syncthreads();
    for (int s = 128; s > 0; s >>= 1) {
        if (threadIdx.x < s) red[threadIdx.x] += red[threadIdx.x + s];
        __syncthreads();
    }
    if (threadIdx.x == 0) out[0] = red[0] / (4096.0f + 1e-5f);
}

extern "C" void kernel_launch(void* const* d_in, const int* in_sizes, int n_in,
                              void* d_out, int out_size, void* d_ws, size_t ws_size,
                              hipStream_t stream) {
    const float* hidden = (const float*)d_in[0];
    const float* Wc     = (const float*)d_in[1];
    const float* bc     = (const float*)d_in[2];
    const float* Wp     = (const float*)d_in[3];
    const float* bp     = (const float*)d_in[4];
    const float* Wo     = (const float*)d_in[5];
    const float* bo     = (const float*)d_in[6];
    const float* dp     = (const float*)d_in[7];
    const int* begins   = (const int*)d_in[8];
    const int* ends     = (const int*)d_in[9];
    const int* bids     = (const int*)d_in[10];
    const int* tags     = (const int*)d_in[11];
    float* out = (float*)d_out;

    // workspace carve (all 16B-aligned)
    u16* Wo_b    = (u16*)d_ws;
    u16* Wc_b    = Wo_b + 16384000;      // 32000*512
    u16* Wp_b    = Wc_b + 524288;        // 512*1024
    u16* ctx_b   = Wp_b + 524288;
    u16* phr_b   = ctx_b + 2097152;      // 2048*1024
    u16* feats_b = phr_b + 2097152;      // 4096*512
    // ps/tlog alias the ctx region (dead after k_feats; in-stream order safe)
    float* ps    = (float*)ctx_b;                 // 4096*100*4 = 1.6MB < 4MB
    float* tlog  = ps + NROWS * NPART;            // 8192

    k_convert<<<2048, 256, 0, stream>>>(Wo, Wo_b, 16384000);
    k_convert<<<256, 256, 0, stream>>>(Wc, Wc_b, 524288);
    k_convert<<<256, 256, 0, stream>>>(Wp, Wp_b, 524288);
    k_gather<<<2048, 256, 0, stream>>>(hidden, begins, ends, bids, ctx_b, phr_b);
    k_feats<<<dim3(32, 8, 2), 256, 0, stream>>>(ctx_b, phr_b, Wc_b, Wp_b, bc, bp, feats_b);
    k_lse<<<dim3(32, NCHUNK), 256, 0, stream>>>(feats_b, Wo_b, bo, ps);
    k_taglog<<<2048, 256, 0, stream>>>(feats_b, Wo_b, bo, tags, tlog);
    k_final<<<1, 256, 0, stream>>>(ps, tlog, tags, dp, out);
}

// Round 7
// 384.035 us; speedup vs baseline: 1.8756x; 1.2296x over previous
//
#include <hip/hip_runtime.h>
#include <stdint.h>

typedef uint16_t u16;
typedef __bf16 bf16x8 __attribute__((ext_vector_type(8)));
typedef float f32x4 __attribute__((ext_vector_type(4)));

#define NCHUNK 50            // 250 tiles / 5 per chunk
#define TILES_PER_CHUNK 5
#define NPART  (2 * NCHUNK)  // 2 col-half waves write separate partials
#define NROWS  4096          // 2L
#define NROUND (TILES_PER_CHUNK * 8)   // BK=64 -> 8 rounds per tile

__device__ __forceinline__ u16 f2b(float x) {
    uint32_t u = __float_as_uint(x);
    u += 0x7FFF + ((u >> 16) & 1);
    return (u16)(u >> 16);
}
__device__ __forceinline__ float b2f(u16 h) {
    return __uint_as_float(((uint32_t)h) << 16);
}

// async global->LDS, 16B per lane. LDS side must be wave-uniform base + lane*16.
__device__ __forceinline__ void cp16(const void* g, void* l) {
    __builtin_amdgcn_global_load_lds(
        (const __attribute__((address_space(1))) uint32_t*)g,
        (__attribute__((address_space(3))) uint32_t*)l, 16, 0, 0);
}

__device__ __forceinline__ float fast_tanh(float x) {
    x = fminf(15.f, fmaxf(-15.f, x));
    float e = __expf(2.f * x);
    return (e - 1.f) / (e + 1.f);
}

// fp32 -> bf16 (RNE), 4 elems/thread grid-stride
__global__ void k_convert(const float* __restrict__ src, u16* __restrict__ dst, int n) {
    int i = (blockIdx.x * blockDim.x + threadIdx.x) * 4;
    int stride = gridDim.x * blockDim.x * 4;
    for (; i < n; i += stride) {
        float4 v = *(const float4*)(src + i);
        u16 o[4] = {f2b(v.x), f2b(v.y), f2b(v.z), f2b(v.w)};
        *(uint64_t*)(dst + i) = *(const uint64_t*)o;
    }
}

// span gathers -> bf16 context/phrase matrices [2048][1024], float4 vectorized
__global__ void k_gather(const float* __restrict__ hidden, const int* __restrict__ begins,
                         const int* __restrict__ ends, const int* __restrict__ bids,
                         u16* __restrict__ ctx, u16* __restrict__ phr) {
    int l = blockIdx.x;
    int b = begins[l], e = ends[l], bd = bids[l];
    const float* h_bm1 = hidden + ((size_t)(b - 1) * 32 + bd) * 1024;
    const float* h_e   = hidden + ((size_t)e * 32 + bd) * 1024;
    const float* h_b   = hidden + ((size_t)b * 32 + bd) * 1024;
    const float* h_em1 = hidden + ((size_t)(e - 1) * 32 + bd) * 1024;
    int d = threadIdx.x * 4;   // 256 threads x 4 = 1024
    float4 c4 = (d < 512) ? *(const float4*)(h_bm1 + d) : *(const float4*)(h_e + d);
    float4 b4 = *(const float4*)(h_b + d);
    float4 e4 = *(const float4*)(h_em1 + d);
    u16 co[4] = {f2b(c4.x), f2b(c4.y), f2b(c4.z), f2b(c4.w)};
    u16 po[4] = {f2b(0.5f * (b4.x + e4.x)), f2b(0.5f * (b4.y + e4.y)),
                 f2b(0.5f * (b4.z + e4.z)), f2b(0.5f * (b4.w + e4.w))};
    *(uint64_t*)(ctx + (size_t)l * 1024 + d) = *(const uint64_t*)co;
    *(uint64_t*)(phr + (size_t)l * 1024 + d) = *(const uint64_t*)po;
}

// feats[z*2048 + m][n] = tanh(A[m] . W[n] + bias[n]),  A:[2048][1024] W:[512][1024]
__global__ __launch_bounds__(256) void k_feats(const u16* __restrict__ ctx, const u16* __restrict__ phr,
        const u16* __restrict__ Wc, const u16* __restrict__ Wp,
        const float* __restrict__ bc, const float* __restrict__ bp,
        u16* __restrict__ feats) {
    __shared__ __align__(16) u16 lA[64 * 32];
    __shared__ __align__(16) u16 lB[64 * 32];
    int z = blockIdx.z;
    const u16* A = z ? phr : ctx;
    const u16* W = z ? Wp : Wc;
    const float* bias = z ? bp : bc;
    int m0 = blockIdx.x * 64;
    int n0 = blockIdx.y * 64;
    int t = threadIdx.x;
    int lane = t & 63, w = t >> 6;
    int lrow = lane & 15, lq = lane >> 4;
    f32x4 zero = {0.f, 0.f, 0.f, 0.f};
    f32x4 acc[4];
    for (int i = 0; i < 4; i++) acc[i] = zero;
    int row = t >> 2, kseg = (t & 3) * 8;
    for (int kt = 0; kt < 32; kt++) {
        int k0 = kt * 32;
        __syncthreads();
        cp16(&A[(size_t)(m0 + row) * 1024 + k0 + kseg], &lA[t * 8]);
        cp16(&W[(size_t)(n0 + row) * 1024 + k0 + kseg], &lB[t * 8]);
        __syncthreads();
        bf16x8 af = *(bf16x8*)&lA[(w * 16 + lrow) * 32 + lq * 8];
        for (int ns = 0; ns < 4; ns++) {
            bf16x8 bfr = *(bf16x8*)&lB[(ns * 16 + lrow) * 32 + lq * 8];
            acc[ns] = __builtin_amdgcn_mfma_f32_16x16x32_bf16(af, bfr, acc[ns], 0, 0, 0);
        }
    }
    int zbase = z * 2048;
    for (int ns = 0; ns < 4; ns++) {
        int col = n0 + ns * 16 + lrow;
        float bv = bias[col];
        for (int r = 0; r < 4; r++) {
            int orow = zbase + m0 + w * 16 + lq * 4 + r;
            feats[(size_t)orow * 512 + col] = f2b(fast_tanh(acc[ns][r] + bv));
        }
    }
}

// big GEMM + row sum-of-exp: feats[4096][512] @ Wo_b[32000][512]^T
// grid (32 m-tiles, 50 chunks of 5 col-tiles); block 256 = 4 waves in 2x2,
// wave tile 64x64 (acc[4][4]). BK=64, ONE barrier per round, double-buffered
// LDS (64 KB): cp16 for round r+1 issued before computing round r, so the
// vmcnt drain at the next barrier is hidden behind 32 MFMAs.
// LDS layout XOR-swizzled: 16B slot' = slot ^ (row&7) with 128 B row stride
// -> each 16-lane b128 phase hits all 8 bank-groups exactly twice (conflict-free).
// No max-tracking: |logit| <= 512/sqrt(512) = 22.6, exp never overflows.
// Col-half waves (w>>1) write separate partial slots, merged in k_final.
__global__ __launch_bounds__(256) void k_lse(const u16* __restrict__ feats,
        const u16* __restrict__ Wo, const float* __restrict__ bo, float* __restrict__ ps) {
    __shared__ __align__(16) u16 lds[2][2][128 * 64];   // [buf][A=0,B=1], 64 KB
    int m0 = blockIdx.x * 128;
    int chunk = blockIdx.y;
    int t = threadIdx.x;
    int lane = t & 63, w = t >> 6;
    int lrow = lane & 15, lq = lane >> 4;
    int wrow = (w & 1) * 64, wcol = (w >> 1) * 64;
    int xm = lrow & 7;
    int x0 = (lq ^ xm) * 16;          // byte slot offset, k-half 0
    int x1 = ((lq + 4) ^ xm) * 16;    // k-half 1

    // staging constants: seg s = t + 256j -> row s>>3 = (t>>3)+32j, slot s&7 = t&7
    // global 8-elem k-part = slot ^ (row&7) = (t&7) ^ ((t>>3)&7)  (j-independent)
    int srow = t >> 3;
    int kp = ((t & 7) ^ ((t >> 3) & 7)) * 8;
    const u16* pA = feats + (size_t)(m0 + srow) * 512 + kp;

    // preload bo for all tiles
    float bov[TILES_PER_CHUNK][4];
    for (int tile = 0; tile < TILES_PER_CHUNK; tile++) {
        int n0 = (chunk * TILES_PER_CHUNK + tile) * 128;
        for (int ni = 0; ni < 4; ni++)
            bov[tile][ni] = bo[n0 + wcol + ni * 16 + lrow];
    }

    float s_state[4][4];
    for (int mi = 0; mi < 4; mi++)
        for (int r = 0; r < 4; r++) s_state[mi][r] = 0.f;
    f32x4 zero = {0.f, 0.f, 0.f, 0.f};
    f32x4 acc[4][4];

    auto stage = [&](int buf, int rr) {
        int tile = rr >> 3;
        int k0 = (rr & 7) * 64;
        int n0 = (chunk * TILES_PER_CHUNK + tile) * 128;
        const u16* pB = Wo + (size_t)(n0 + srow) * 512 + kp;
        for (int j = 0; j < 4; j++) {
            cp16(pA + (size_t)(32 * j) * 512 + k0, &lds[buf][0][t * 8 + j * 2048]);
            cp16(pB + (size_t)(32 * j) * 512 + k0, &lds[buf][1][t * 8 + j * 2048]);
        }
    };

    stage(0, 0);
    for (int rr = 0; rr < NROUND; rr++) {
        int cur = rr & 1;
        __syncthreads();                    // drains cp16s of buf[cur]
        if (rr + 1 < NROUND) stage(cur ^ 1, rr + 1);
        if ((rr & 7) == 0)
            for (int mi = 0; mi < 4; mi++)
                for (int ni = 0; ni < 4; ni++) acc[mi][ni] = zero;
        const char* bufA = (const char*)lds[cur][0];
        const char* bufB = (const char*)lds[cur][1];
        for (int ks = 0; ks < 2; ks++) {
            int xo = ks ? x1 : x0;
            bf16x8 af[4];
            for (int mi = 0; mi < 4; mi++)
                af[mi] = *(const bf16x8*)(bufA + (wrow + mi * 16 + lrow) * 128 + xo);
            for (int ni = 0; ni < 4; ni++) {
                bf16x8 bfr = *(const bf16x8*)(bufB + (wcol + ni * 16 + lrow) * 128 + xo);
                for (int mi = 0; mi < 4; mi++)
                    acc[mi][ni] = __builtin_amdgcn_mfma_f32_16x16x32_bf16(af[mi], bfr, acc[mi][ni], 0, 0, 0);
            }
        }
        if ((rr & 7) == 7) {
            int tile = rr >> 3;
            for (int ni = 0; ni < 4; ni++) {
                float bv = bov[tile][ni];
                for (int mi = 0; mi < 4; mi++)
                    for (int r = 0; r < 4; r++)
                        s_state[mi][r] += __expf(acc[mi][ni][r] + bv);
            }
        }
    }
    // merge cols across the 16 lanes of each quad-group (xor 1,2,4,8 stays in-group)
    for (int mi = 0; mi < 4; mi++)
    for (int r = 0; r < 4; r++) {
        float s = s_state[mi][r];
        for (int off = 1; off < 16; off <<= 1) s += __shfl_xor(s, off);
        if (lrow == 0) {
            int row = m0 + wrow + mi * 16 + lq * 4 + r;
            ps[row * NPART + chunk * 2 + (w >> 1)] = s;
        }
    }
}

// tag logits: one wave per row does BOTH tags (reuses the feats row)
__global__ void k_taglog(const u16* __restrict__ feats, const u16* __restrict__ Wo,
        const float* __restrict__ bo, const int* __restrict__ tags, float* __restrict__ tlog) {
    int i = blockIdx.x * 4 + (threadIdx.x >> 6);   // row 0..4095
    int lane = threadIdx.x & 63;
    int t0 = tags[(i & 2047) * 2 + 0];
    int t1 = tags[(i & 2047) * 2 + 1];
    union { int4 v; u16 h[8]; } fa, wa0, wa1;
    fa.v  = *(const int4*)(feats + (size_t)i * 512 + lane * 8);
    wa0.v = *(const int4*)(Wo + (size_t)t0 * 512 + lane * 8);
    wa1.v = *(const int4*)(Wo + (size_t)t1 * 512 + lane * 8);
    float s0 = 0.f, s1 = 0.f;
    for (int j = 0; j < 8; j++) {
        float f = b2f(fa.h[j]);
        s0 += f * b2f(wa0.h[j]);
        s1 += f * b2f(wa1.h[j]);
    }
    for (int off = 32; off >= 1; off >>= 1) {
        s0 += __shfl_down(s0, off);
        s1 += __shfl_down(s1, off);
    }
    if (lane == 0) {
        tlog[i * 2 + 0] = s0 + bo[t0];
        tlog[i * 2 + 1] = s1 + bo[t1];
    }
}

__global__ void k_zero(float* __restrict__ out) { out[0] = 0.f; }

// lse = log(sum of chunk partials) + loss; 16 blocks x 256 rows, atomicAdd
__global__ void k_final(const float* __restrict__ ps,
        const float* __restrict__ tlog, const int* __restrict__ tags,
        const float* __restrict__ dp, float* __restrict__ out) {
    __shared__ float red[256];
    int i = blockIdx.x * 256 + threadIdx.x;
    float S = 0.f;
    for (int j = 0; j < NPART; j++) S += ps[i * NPART + j];
    float lse = logf(S);
    float num = 0.f, den = 0.f;
    for (int k = 0; k < 2; k++) {
        int tg = tags[(i & 2047) * 2 + k];
        float r = 1.0f - dp[tg];
        num += r * (lse - tlog[i * 2 + k]);
        den += r;
    }
    red[threadIdx.x] = num / den;
    __syncthreads();
    for (int s = 128; s > 0; s >>= 1) {
        if (threadIdx.x < s) red[threadIdx.x] += red[threadIdx.x + s];
        __syncthreads();
    }
    if (threadIdx.x == 0) atomicAdd(out, red[0] / (4096.0f + 1e-5f));
}

extern "C" void kernel_launch(void* const* d_in, const int* in_sizes, int n_in,
                              void* d_out, int out_size, void* d_ws, size_t ws_size,
                              hipStream_t stream) {
    const float* hidden = (const float*)d_in[0];
    const float* Wc     = (const float*)d_in[1];
    const float* bc     = (const float*)d_in[2];
    const float* Wp     = (const float*)d_in[3];
    const float* bp     = (const float*)d_in[4];
    const float* Wo     = (const float*)d_in[5];
    const float* bo     = (const float*)d_in[6];
    const float* dp     = (const float*)d_in[7];
    const int* begins   = (const int*)d_in[8];
    const int* ends     = (const int*)d_in[9];
    const int* bids     = (const int*)d_in[10];
    const int* tags     = (const int*)d_in[11];
    float* out = (float*)d_out;

    // workspace carve (all 16B-aligned)
    u16* Wo_b    = (u16*)d_ws;
    u16* Wc_b    = Wo_b + 16384000;      // 32000*512
    u16* Wp_b    = Wc_b + 524288;        // 512*1024
    u16* ctx_b   = Wp_b + 524288;
    u16* phr_b   = ctx_b + 2097152;      // 2048*1024
    u16* feats_b = phr_b + 2097152;      // 4096*512
    // ps/tlog alias the ctx region (dead after k_feats; in-stream order safe)
    float* ps    = (float*)ctx_b;                 // 4096*100*4 = 1.6MB < 4MB
    float* tlog  = ps + NROWS * NPART;            // 8192

    k_convert<<<2048, 256, 0, stream>>>(Wo, Wo_b, 16384000);
    k_convert<<<256, 256, 0, stream>>>(Wc, Wc_b, 524288);
    k_convert<<<256, 256, 0, stream>>>(Wp, Wp_b, 524288);
    k_gather<<<2048, 256, 0, stream>>>(hidden, begins, ends, bids, ctx_b, phr_b);
    k_feats<<<dim3(32, 8, 2), 256, 0, stream>>>(ctx_b, phr_b, Wc_b, Wp_b, bc, bp, feats_b);
    k_lse<<<dim3(32, NCHUNK), 256, 0, stream>>>(feats_b, Wo_b, bo, ps);
    k_taglog<<<1024, 256, 0, stream>>>(feats_b, Wo_b, bo, tags, tlog);
    k_zero<<<1, 1, 0, stream>>>(out);
    k_final<<<16, 256, 0, stream>>>(ps, tlog, tags, dp, out);
}

// Round 8
// 372.537 us; speedup vs baseline: 1.9335x; 1.0309x over previous
//
#include <hip/hip_runtime.h>
#include <stdint.h>

typedef uint16_t u16;
typedef __bf16 bf16x8 __attribute__((ext_vector_type(8)));
typedef float f32x4 __attribute__((ext_vector_type(4)));

#define NSC    16            // persistent super-chunks (grid y)
#define NTILES 250           // 32000/128 n-tiles
#define NPART  (2 * NSC)     // 2 col-half waves x 16 super-chunks
#define NROWS  4096          // 2L

__device__ __forceinline__ u16 f2b(float x) {
    uint32_t u = __float_as_uint(x);
    u += 0x7FFF + ((u >> 16) & 1);
    return (u16)(u >> 16);
}
__device__ __forceinline__ float b2f(u16 h) {
    return __uint_as_float(((uint32_t)h) << 16);
}

// async global->LDS, 16B per lane. LDS side must be wave-uniform base + lane*16.
__device__ __forceinline__ void cp16(const void* g, void* l) {
    __builtin_amdgcn_global_load_lds(
        (const __attribute__((address_space(1))) uint32_t*)g,
        (__attribute__((address_space(3))) uint32_t*)l, 16, 0, 0);
}

__device__ __forceinline__ float fast_tanh(float x) {
    x = fminf(15.f, fmaxf(-15.f, x));
    float e = __expf(2.f * x);
    return (e - 1.f) / (e + 1.f);
}

// fp32 -> bf16 (RNE), 4 elems/thread grid-stride
__global__ void k_convert(const float* __restrict__ src, u16* __restrict__ dst, int n) {
    int i = (blockIdx.x * blockDim.x + threadIdx.x) * 4;
    int stride = gridDim.x * blockDim.x * 4;
    for (; i < n; i += stride) {
        float4 v = *(const float4*)(src + i);
        u16 o[4] = {f2b(v.x), f2b(v.y), f2b(v.z), f2b(v.w)};
        *(uint64_t*)(dst + i) = *(const uint64_t*)o;
    }
}

// span gathers -> bf16 context/phrase matrices [2048][1024], float4 vectorized
__global__ void k_gather(const float* __restrict__ hidden, const int* __restrict__ begins,
                         const int* __restrict__ ends, const int* __restrict__ bids,
                         u16* __restrict__ ctx, u16* __restrict__ phr) {
    int l = blockIdx.x;
    int b = begins[l], e = ends[l], bd = bids[l];
    const float* h_bm1 = hidden + ((size_t)(b - 1) * 32 + bd) * 1024;
    const float* h_e   = hidden + ((size_t)e * 32 + bd) * 1024;
    const float* h_b   = hidden + ((size_t)b * 32 + bd) * 1024;
    const float* h_em1 = hidden + ((size_t)(e - 1) * 32 + bd) * 1024;
    int d = threadIdx.x * 4;   // 256 threads x 4 = 1024
    float4 c4 = (d < 512) ? *(const float4*)(h_bm1 + d) : *(const float4*)(h_e + d);
    float4 b4 = *(const float4*)(h_b + d);
    float4 e4 = *(const float4*)(h_em1 + d);
    u16 co[4] = {f2b(c4.x), f2b(c4.y), f2b(c4.z), f2b(c4.w)};
    u16 po[4] = {f2b(0.5f * (b4.x + e4.x)), f2b(0.5f * (b4.y + e4.y)),
                 f2b(0.5f * (b4.z + e4.z)), f2b(0.5f * (b4.w + e4.w))};
    *(uint64_t*)(ctx + (size_t)l * 1024 + d) = *(const uint64_t*)co;
    *(uint64_t*)(phr + (size_t)l * 1024 + d) = *(const uint64_t*)po;
}

// feats[z*2048 + m][n] = tanh(A[m] . W[n] + bias[n]),  A:[2048][1024] W:[512][1024]
__global__ __launch_bounds__(256) void k_feats(const u16* __restrict__ ctx, const u16* __restrict__ phr,
        const u16* __restrict__ Wc, const u16* __restrict__ Wp,
        const float* __restrict__ bc, const float* __restrict__ bp,
        u16* __restrict__ feats) {
    __shared__ __align__(16) u16 lA[64 * 32];
    __shared__ __align__(16) u16 lB[64 * 32];
    int z = blockIdx.z;
    const u16* A = z ? phr : ctx;
    const u16* W = z ? Wp : Wc;
    const float* bias = z ? bp : bc;
    int m0 = blockIdx.x * 64;
    int n0 = blockIdx.y * 64;
    int t = threadIdx.x;
    int lane = t & 63, w = t >> 6;
    int lrow = lane & 15, lq = lane >> 4;
    f32x4 zero = {0.f, 0.f, 0.f, 0.f};
    f32x4 acc[4];
    for (int i = 0; i < 4; i++) acc[i] = zero;
    int row = t >> 2, kseg = (t & 3) * 8;
    for (int kt = 0; kt < 32; kt++) {
        int k0 = kt * 32;
        __syncthreads();
        cp16(&A[(size_t)(m0 + row) * 1024 + k0 + kseg], &lA[t * 8]);
        cp16(&W[(size_t)(n0 + row) * 1024 + k0 + kseg], &lB[t * 8]);
        __syncthreads();
        bf16x8 af = *(bf16x8*)&lA[(w * 16 + lrow) * 32 + lq * 8];
        for (int ns = 0; ns < 4; ns++) {
            bf16x8 bfr = *(bf16x8*)&lB[(ns * 16 + lrow) * 32 + lq * 8];
            acc[ns] = __builtin_amdgcn_mfma_f32_16x16x32_bf16(af, bfr, acc[ns], 0, 0, 0);
        }
    }
    int zbase = z * 2048;
    for (int ns = 0; ns < 4; ns++) {
        int col = n0 + ns * 16 + lrow;
        float bv = bias[col];
        for (int r = 0; r < 4; r++) {
            int orow = zbase + m0 + w * 16 + lq * 4 + r;
            feats[(size_t)orow * 512 + col] = f2b(fast_tanh(acc[ns][r] + bv));
        }
    }
}

// big GEMM + row sum-of-exp: feats[4096][512] @ Wo_b[32000][512]^T
// PERSISTENT: grid (32 m-tiles, 16 super-chunks) = 512 blocks = exactly
// 2/CU resident; each block sweeps its ~15-16 n-tiles in ONE continuous
// double-buffered round loop (BK=64, one barrier/round, cp16 for round r+1
// issued before computing round r). 4 waves in 2x2, wave tile 64x64.
// LDS XOR-swizzle (slot' = slot ^ (row&7), 128B row stride): conflict-free
// (R7 measured SQ_LDS_BANK_CONFLICT = 0).
// No max-tracking: |logit| <= 512/sqrt(512) = 22.6, exp never overflows.
// Col-half waves (w>>1) write separate partial slots, merged in k_final.
__global__ __launch_bounds__(256) void k_lse(const u16* __restrict__ feats,
        const u16* __restrict__ Wo, const float* __restrict__ bo, float* __restrict__ ps) {
    __shared__ __align__(16) u16 lds[2][2][128 * 64];   // [buf][A=0,B=1], 64 KB
    int m0 = blockIdx.x * 128;
    int sc = blockIdx.y;
    int ts = (NTILES * sc) / NSC, te = (NTILES * (sc + 1)) / NSC;
    int t = threadIdx.x;
    int lane = t & 63, w = t >> 6;
    int lrow = lane & 15, lq = lane >> 4;
    int wrow = (w & 1) * 64, wcol = (w >> 1) * 64;
    int xm = lrow & 7;
    int x0 = (lq ^ xm) * 16;          // byte slot offset, k-half 0
    int x1 = ((lq + 4) ^ xm) * 16;    // k-half 1

    // staging constants: seg s = t + 256j -> row s>>3 = (t>>3)+32j, slot s&7 = t&7
    // global 8-elem k-part = slot ^ (row&7) = (t&7) ^ ((t>>3)&7)  (j-independent)
    int srow = t >> 3;
    int kp = ((t & 7) ^ ((t >> 3) & 7)) * 8;
    const u16* pA = feats + (size_t)(m0 + srow) * 512 + kp;

    float s_state[4][4];
    for (int mi = 0; mi < 4; mi++)
        for (int r = 0; r < 4; r++) s_state[mi][r] = 0.f;
    f32x4 zero = {0.f, 0.f, 0.f, 0.f};
    f32x4 acc[4][4];

    auto stage = [&](int buf, int gr) {
        int tile = gr >> 3;
        int k0 = (gr & 7) * 64;
        const u16* pB = Wo + (size_t)(tile * 128 + srow) * 512 + kp;
        for (int j = 0; j < 4; j++) {
            cp16(pA + (size_t)(32 * j) * 512 + k0, &lds[buf][0][t * 8 + j * 2048]);
            cp16(pB + (size_t)(32 * j) * 512 + k0, &lds[buf][1][t * 8 + j * 2048]);
        }
    };

    int gr0 = ts * 8, gr1 = te * 8;   // gr0 even -> buffer parity = gr&1
    stage(0, gr0);
    for (int gr = gr0; gr < gr1; gr++) {
        int cur = gr & 1;
        __syncthreads();                    // drains cp16s of buf[cur]
        if (gr + 1 < gr1) stage(cur ^ 1, gr + 1);
        if ((gr & 7) == 0)
            for (int mi = 0; mi < 4; mi++)
                for (int ni = 0; ni < 4; ni++) acc[mi][ni] = zero;
        const char* bufA = (const char*)lds[cur][0];
        const char* bufB = (const char*)lds[cur][1];
        for (int ks = 0; ks < 2; ks++) {
            int xo = ks ? x1 : x0;
            bf16x8 af[4];
            for (int mi = 0; mi < 4; mi++)
                af[mi] = *(const bf16x8*)(bufA + (wrow + mi * 16 + lrow) * 128 + xo);
            for (int ni = 0; ni < 4; ni++) {
                bf16x8 bfr = *(const bf16x8*)(bufB + (wcol + ni * 16 + lrow) * 128 + xo);
                for (int mi = 0; mi < 4; mi++)
                    acc[mi][ni] = __builtin_amdgcn_mfma_f32_16x16x32_bf16(af[mi], bfr, acc[mi][ni], 0, 0, 0);
            }
        }
        if ((gr & 7) == 7) {
            int n0 = (gr >> 3) * 128;
            for (int ni = 0; ni < 4; ni++) {
                float bv = bo[n0 + wcol + ni * 16 + lrow];
                for (int mi = 0; mi < 4; mi++)
                    for (int r = 0; r < 4; r++)
                        s_state[mi][r] += __expf(acc[mi][ni][r] + bv);
            }
        }
    }
    // merge cols across the 16 lanes of each quad-group (xor 1,2,4,8 stays in-group)
    for (int mi = 0; mi < 4; mi++)
    for (int r = 0; r < 4; r++) {
        float s = s_state[mi][r];
        for (int off = 1; off < 16; off <<= 1) s += __shfl_xor(s, off);
        if (lrow == 0) {
            int row = m0 + wrow + mi * 16 + lq * 4 + r;
            ps[row * NPART + sc * 2 + (w >> 1)] = s;
        }
    }
}

// tag logits: one wave per row does BOTH tags (reuses the feats row)
__global__ void k_taglog(const u16* __restrict__ feats, const u16* __restrict__ Wo,
        const float* __restrict__ bo, const int* __restrict__ tags, float* __restrict__ tlog) {
    int i = blockIdx.x * 4 + (threadIdx.x >> 6);   // row 0..4095
    int lane = threadIdx.x & 63;
    int t0 = tags[(i & 2047) * 2 + 0];
    int t1 = tags[(i & 2047) * 2 + 1];
    union { int4 v; u16 h[8]; } fa, wa0, wa1;
    fa.v  = *(const int4*)(feats + (size_t)i * 512 + lane * 8);
    wa0.v = *(const int4*)(Wo + (size_t)t0 * 512 + lane * 8);
    wa1.v = *(const int4*)(Wo + (size_t)t1 * 512 + lane * 8);
    float s0 = 0.f, s1 = 0.f;
    for (int j = 0; j < 8; j++) {
        float f = b2f(fa.h[j]);
        s0 += f * b2f(wa0.h[j]);
        s1 += f * b2f(wa1.h[j]);
    }
    for (int off = 32; off >= 1; off >>= 1) {
        s0 += __shfl_down(s0, off);
        s1 += __shfl_down(s1, off);
    }
    if (lane == 0) {
        tlog[i * 2 + 0] = s0 + bo[t0];
        tlog[i * 2 + 1] = s1 + bo[t1];
    }
}

__global__ void k_zero(float* __restrict__ out) { out[0] = 0.f; }

// lse = log(sum of chunk partials) + loss; 16 blocks x 256 rows, atomicAdd
__global__ void k_final(const float* __restrict__ ps,
        const float* __restrict__ tlog, const int* __restrict__ tags,
        const float* __restrict__ dp, float* __restrict__ out) {
    __shared__ float red[256];
    int i = blockIdx.x * 256 + threadIdx.x;
    float S = 0.f;
    for (int j = 0; j < NPART; j++) S += ps[i * NPART + j];
    float lse = logf(S);
    float num = 0.f, den = 0.f;
    for (int k = 0; k < 2; k++) {
        int tg = tags[(i & 2047) * 2 + k];
        float r = 1.0f - dp[tg];
        num += r * (lse - tlog[i * 2 + k]);
        den += r;
    }
    red[threadIdx.x] = num / den;
    __syncthreads();
    for (int s = 128; s > 0; s >>= 1) {
        if (threadIdx.x < s) red[threadIdx.x] += red[threadIdx.x + s];
        __syncthreads();
    }
    if (threadIdx.x == 0) atomicAdd(out, red[0] / (4096.0f + 1e-5f));
}

extern "C" void kernel_launch(void* const* d_in, const int* in_sizes, int n_in,
                              void* d_out, int out_size, void* d_ws, size_t ws_size,
                              hipStream_t stream) {
    const float* hidden = (const float*)d_in[0];
    const float* Wc     = (const float*)d_in[1];
    const float* bc     = (const float*)d_in[2];
    const float* Wp     = (const float*)d_in[3];
    const float* bp     = (const float*)d_in[4];
    const float* Wo     = (const float*)d_in[5];
    const float* bo     = (const float*)d_in[6];
    const float* dp     = (const float*)d_in[7];
    const int* begins   = (const int*)d_in[8];
    const int* ends     = (const int*)d_in[9];
    const int* bids     = (const int*)d_in[10];
    const int* tags     = (const int*)d_in[11];
    float* out = (float*)d_out;

    // workspace carve (all 16B-aligned)
    u16* Wo_b    = (u16*)d_ws;
    u16* Wc_b    = Wo_b + 16384000;      // 32000*512
    u16* Wp_b    = Wc_b + 524288;        // 512*1024
    u16* ctx_b   = Wp_b + 524288;
    u16* phr_b   = ctx_b + 2097152;      // 2048*1024
    u16* feats_b = phr_b + 2097152;      // 4096*512
    // ps/tlog alias the ctx region (dead after k_feats; in-stream order safe)
    float* ps    = (float*)ctx_b;                 // 4096*32*4 = 512KB
    float* tlog  = ps + NROWS * NPART;            // 8192

    k_convert<<<2048, 256, 0, stream>>>(Wo, Wo_b, 16384000);
    k_convert<<<256, 256, 0, stream>>>(Wc, Wc_b, 524288);
    k_convert<<<256, 256, 0, stream>>>(Wp, Wp_b, 524288);
    k_gather<<<2048, 256, 0, stream>>>(hidden, begins, ends, bids, ctx_b, phr_b);
    k_feats<<<dim3(32, 8, 2), 256, 0, stream>>>(ctx_b, phr_b, Wc_b, Wp_b, bc, bp, feats_b);
    k_lse<<<dim3(32, NSC), 256, 0, stream>>>(feats_b, Wo_b, bo, ps);
    k_taglog<<<1024, 256, 0, stream>>>(feats_b, Wo_b, bo, tags, tlog);
    k_zero<<<1, 1, 0, stream>>>(out);
    k_final<<<16, 256, 0, stream>>>(ps, tlog, tags, dp, out);
}

// Round 9
// 310.755 us; speedup vs baseline: 2.3179x; 1.1988x over previous
//
#include <hip/hip_runtime.h>
#include <stdint.h>

typedef uint16_t u16;
typedef uint8_t  u8;
typedef __bf16 bf16x8 __attribute__((ext_vector_type(8)));
typedef float f32x4 __attribute__((ext_vector_type(4)));

#define NSC    16            // persistent super-chunks (grid y)
#define NTILES 250           // 32000/128 n-tiles
#define NPART  (2 * NSC)     // 2 col-half waves x 16 super-chunks
#define NROWS  4096          // 2L

__device__ __forceinline__ u16 f2b(float x) {
    uint32_t u = __float_as_uint(x);
    u += 0x7FFF + ((u >> 16) & 1);
    return (u16)(u >> 16);
}

// fp32 -> fp8 e4m3fn (OCP), RNE, clamp to +-448. Hand-rolled (no builtin risk).
__device__ __forceinline__ u8 f32_to_fp8(float x) {
    uint32_t sign = (__float_as_uint(x) >> 24) & 0x80;
    float ax = fminf(fabsf(x), 448.f);
    uint32_t r;
    if (ax < 0.015625f) {                      // subnormal: m * 2^-9
        r = (uint32_t)(int)rintf(ax * 512.f);  // rolls to 0x08 (=2^-6) at 8: still correct
    } else {
        uint32_t u = __float_as_uint(ax);
        u += 0x0007FFFF + ((u >> 20) & 1);     // RNE into 3-bit mantissa
        r = (((u >> 23) - 120) << 3) | ((u >> 20) & 7);
    }
    return (u8)(sign | r);
}

// fp8 e4m3fn -> fp32 (exact)
__device__ __forceinline__ float fp8_val(int b) {
    int e = (b >> 3) & 0xF, m = b & 7;
    float v = e ? __uint_as_float((uint32_t)(((e + 120) << 23) | (m << 20)))
                : (float)m * 0.001953125f;
    return (b & 0x80) ? -v : v;
}

// async global->LDS, 16B per lane. LDS side must be wave-uniform base + lane*16.
__device__ __forceinline__ void cp16(const void* g, void* l) {
    __builtin_amdgcn_global_load_lds(
        (const __attribute__((address_space(1))) uint32_t*)g,
        (__attribute__((address_space(3))) uint32_t*)l, 16, 0, 0);
}

__device__ __forceinline__ float fast_tanh(float x) {
    x = fminf(15.f, fmaxf(-15.f, x));
    float e = __expf(2.f * x);
    return (e - 1.f) / (e + 1.f);
}

// Wo fp32 -> fp8 (x32 scale), 4 elems/thread grid-stride
__global__ void k_convert8(const float* __restrict__ src, u8* __restrict__ dst, int n) {
    int i = (blockIdx.x * blockDim.x + threadIdx.x) * 4;
    int stride = gridDim.x * blockDim.x * 4;
    for (; i < n; i += stride) {
        float4 v = *(const float4*)(src + i);
        u8 o[4] = {f32_to_fp8(v.x * 32.f), f32_to_fp8(v.y * 32.f),
                   f32_to_fp8(v.z * 32.f), f32_to_fp8(v.w * 32.f)};
        *(uint32_t*)(dst + i) = *(const uint32_t*)o;
    }
}

// fused prep: blocks 0..255 convert Wc+Wp fp32->bf16 (8 elems/thread each);
// blocks 256..2303 do the span gathers -> bf16 ctx/phr
__global__ void k_prep(const float* __restrict__ Wc, const float* __restrict__ Wp,
                       const float* __restrict__ hidden, const int* __restrict__ begins,
                       const int* __restrict__ ends, const int* __restrict__ bids,
                       u16* __restrict__ Wc_b, u16* __restrict__ Wp_b,
                       u16* __restrict__ ctx, u16* __restrict__ phr) {
    int b = blockIdx.x;
    if (b < 256) {
        int i = b * 2048 + threadIdx.x * 8;
        float4 a0 = *(const float4*)(Wc + i), a1 = *(const float4*)(Wc + i + 4);
        float4 p0 = *(const float4*)(Wp + i), p1 = *(const float4*)(Wp + i + 4);
        u16 oc[8] = {f2b(a0.x), f2b(a0.y), f2b(a0.z), f2b(a0.w),
                     f2b(a1.x), f2b(a1.y), f2b(a1.z), f2b(a1.w)};
        u16 op[8] = {f2b(p0.x), f2b(p0.y), f2b(p0.z), f2b(p0.w),
                     f2b(p1.x), f2b(p1.y), f2b(p1.z), f2b(p1.w)};
        *(int4*)(Wc_b + i) = *(const int4*)oc;
        *(int4*)(Wp_b + i) = *(const int4*)op;
        return;
    }
    int l = b - 256;
    int bg = begins[l], e = ends[l], bd = bids[l];
    const float* h_bm1 = hidden + ((size_t)(bg - 1) * 32 + bd) * 1024;
    const float* h_e   = hidden + ((size_t)e * 32 + bd) * 1024;
    const float* h_b   = hidden + ((size_t)bg * 32 + bd) * 1024;
    const float* h_em1 = hidden + ((size_t)(e - 1) * 32 + bd) * 1024;
    int d = threadIdx.x * 4;
    float4 c4 = (d < 512) ? *(const float4*)(h_bm1 + d) : *(const float4*)(h_e + d);
    float4 b4 = *(const float4*)(h_b + d);
    float4 e4 = *(const float4*)(h_em1 + d);
    u16 co[4] = {f2b(c4.x), f2b(c4.y), f2b(c4.z), f2b(c4.w)};
    u16 po[4] = {f2b(0.5f * (b4.x + e4.x)), f2b(0.5f * (b4.y + e4.y)),
                 f2b(0.5f * (b4.z + e4.z)), f2b(0.5f * (b4.w + e4.w))};
    *(uint64_t*)(ctx + (size_t)l * 1024 + d) = *(const uint64_t*)co;
    *(uint64_t*)(phr + (size_t)l * 1024 + d) = *(const uint64_t*)po;
}

// feats8[z*2048+m][n] = fp8(16 * tanh(A[m].W[n] + bias[n])), bf16 MFMA inputs
__global__ __launch_bounds__(256) void k_feats(const u16* __restrict__ ctx, const u16* __restrict__ phr,
        const u16* __restrict__ Wc, const u16* __restrict__ Wp,
        const float* __restrict__ bc, const float* __restrict__ bp,
        u8* __restrict__ feats) {
    __shared__ __align__(16) u16 lA[64 * 32];
    __shared__ __align__(16) u16 lB[64 * 32];
    int z = blockIdx.z;
    const u16* A = z ? phr : ctx;
    const u16* W = z ? Wp : Wc;
    const float* bias = z ? bp : bc;
    int m0 = blockIdx.x * 64;
    int n0 = blockIdx.y * 64;
    int t = threadIdx.x;
    int lane = t & 63, w = t >> 6;
    int lrow = lane & 15, lq = lane >> 4;
    f32x4 zero = {0.f, 0.f, 0.f, 0.f};
    f32x4 acc[4];
    for (int i = 0; i < 4; i++) acc[i] = zero;
    int row = t >> 2, kseg = (t & 3) * 8;
    for (int kt = 0; kt < 32; kt++) {
        int k0 = kt * 32;
        __syncthreads();
        cp16(&A[(size_t)(m0 + row) * 1024 + k0 + kseg], &lA[t * 8]);
        cp16(&W[(size_t)(n0 + row) * 1024 + k0 + kseg], &lB[t * 8]);
        __syncthreads();
        bf16x8 af = *(bf16x8*)&lA[(w * 16 + lrow) * 32 + lq * 8];
        for (int ns = 0; ns < 4; ns++) {
            bf16x8 bfr = *(bf16x8*)&lB[(ns * 16 + lrow) * 32 + lq * 8];
            acc[ns] = __builtin_amdgcn_mfma_f32_16x16x32_bf16(af, bfr, acc[ns], 0, 0, 0);
        }
    }
    int zbase = z * 2048;
    for (int ns = 0; ns < 4; ns++) {
        int col = n0 + ns * 16 + lrow;
        float bv = bias[col];
        for (int r = 0; r < 4; r++) {
            int orow = zbase + m0 + w * 16 + lq * 4 + r;
            feats[(size_t)orow * 512 + col] = f32_to_fp8(16.f * fast_tanh(acc[ns][r] + bv));
        }
    }
}

// big GEMM + row sum-of-exp, fp8 path: feats8[4096][512] @ Wo8[32000][512]^T
// (A scaled x16, B x32 -> logit = acc/512). PERSISTENT grid (32,16)=512 blocks
// = 2/CU. BK=128 (one barrier per 64 MFMAs/wave), double-buffered 64 KB LDS.
// Rows 128 B, 16B-slot XOR swizzle (slot' = slot ^ (row&7)) - R7-proven
// conflict-free; frag reads are b64 (2-way per 16-lane phase = free).
// No max-tracking: |logit| <= 22.6, exp never overflows fp32.
// Col-half waves (w>>1) write separate partial slots, merged in k_final.
__global__ __launch_bounds__(256) void k_lse(const u8* __restrict__ feats,
        const u8* __restrict__ Wo, const float* __restrict__ bo, float* __restrict__ ps) {
    __shared__ __align__(16) u8 lds[2][2][128 * 128];   // [buf][A,B] = 64 KB
    int m0 = blockIdx.x * 128;
    int sc = blockIdx.y;
    int ts = (NTILES * sc) / NSC, te = (NTILES * (sc + 1)) / NSC;
    int t = threadIdx.x;
    int lane = t & 63, w = t >> 6;
    int lrow = lane & 15, lq = lane >> 4;
    int wrow = (w & 1) * 64, wcol = (w >> 1) * 64;
    int xm = lrow & 7;                 // swizzle key (row&7 == lrow&7 for our rows)
    int lql = lq >> 1, lqb = (lq & 1) * 8;

    // staging: 1024 16B chunks per matrix, 4 per thread (c = t + 256j).
    // chunk c -> row c>>3, phys slot c&7; source k-chunk = (c&7)^((c>>3)&7),
    // identical for all j since 32j = 0 (mod 8).
    int srow = t >> 3;
    int kb = ((t & 7) ^ ((t >> 3) & 7)) * 16;
    const u8* pA = feats + (size_t)(m0 + srow) * 512 + kb;

    int rowA[4], rowB[4];
    for (int i = 0; i < 4; i++) {
        rowA[i] = (wrow + i * 16 + lrow) * 128;
        rowB[i] = (wcol + i * 16 + lrow) * 128;
    }

    float s_state[4][4];
    for (int mi = 0; mi < 4; mi++)
        for (int r = 0; r < 4; r++) s_state[mi][r] = 0.f;
    f32x4 zero = {0.f, 0.f, 0.f, 0.f};
    f32x4 acc[4][4];
    const float inv512 = 1.f / 512.f;

    auto stage = [&](int buf, int gr) {
        int k0 = (gr & 3) * 128;
        const u8* pB = Wo + (size_t)((gr >> 2) * 128 + srow) * 512 + kb;
        const u8* pA2 = pA + k0;
        for (int j = 0; j < 4; j++) {
            cp16(pA2 + (size_t)(32 * j) * 512, &lds[buf][0][t * 16 + j * 4096]);
            cp16(pB + k0 + (size_t)(32 * j) * 512, &lds[buf][1][t * 16 + j * 4096]);
        }
    };

    int gr0 = ts * 4, gr1 = te * 4;   // gr0 even -> parity gr&1 consistent
    stage(0, gr0);
    for (int gr = gr0; gr < gr1; gr++) {
        int cur = gr & 1;
        __syncthreads();                    // drains cp16s of buf[cur]
        if (gr + 1 < gr1) stage(cur ^ 1, gr + 1);
        if ((gr & 3) == 0)
            for (int mi = 0; mi < 4; mi++)
                for (int ni = 0; ni < 4; ni++) acc[mi][ni] = zero;
        const u8* bufA = lds[cur][0];
        const u8* bufB = lds[cur][1];
        for (int ksl = 0; ksl < 4; ksl++) {
            int xo = (((ksl << 1) + lql) ^ xm) * 16 + lqb;
            long af[4];
            for (int mi = 0; mi < 4; mi++)
                af[mi] = *(const long*)(bufA + rowA[mi] + xo);
            for (int ni = 0; ni < 4; ni++) {
                long bfr = *(const long*)(bufB + rowB[ni] + xo);
                for (int mi = 0; mi < 4; mi++)
                    acc[mi][ni] = __builtin_amdgcn_mfma_f32_16x16x32_fp8_fp8(af[mi], bfr, acc[mi][ni], 0, 0, 0);
            }
        }
        if ((gr & 3) == 3) {
            int n0 = (gr >> 2) * 128;
            for (int ni = 0; ni < 4; ni++) {
                float bv = bo[n0 + wcol + ni * 16 + lrow];
                for (int mi = 0; mi < 4; mi++)
                    for (int r = 0; r < 4; r++)
                        s_state[mi][r] += __expf(fmaf(acc[mi][ni][r], inv512, bv));
            }
        }
    }
    // merge cols across the 16 lanes of each quad-group (xor 1,2,4,8 stays in-group)
    for (int mi = 0; mi < 4; mi++)
    for (int r = 0; r < 4; r++) {
        float s = s_state[mi][r];
        for (int off = 1; off < 16; off <<= 1) s += __shfl_xor(s, off);
        if (lrow == 0) {
            int row = m0 + wrow + mi * 16 + lq * 4 + r;
            ps[row * NPART + sc * 2 + (w >> 1)] = s;
        }
    }
}

// tag logits from fp8: one wave per row does BOTH tags; logit = dot/512 + bo
__global__ void k_taglog(const u8* __restrict__ feats, const u8* __restrict__ Wo,
        const float* __restrict__ bo, const int* __restrict__ tags, float* __restrict__ tlog) {
    int i = blockIdx.x * 4 + (threadIdx.x >> 6);   // row 0..4095
    int lane = threadIdx.x & 63;
    int t0 = tags[(i & 2047) * 2 + 0];
    int t1 = tags[(i & 2047) * 2 + 1];
    uint64_t fa = *(const uint64_t*)(feats + (size_t)i * 512 + lane * 8);
    uint64_t wa = *(const uint64_t*)(Wo + (size_t)t0 * 512 + lane * 8);
    uint64_t wb = *(const uint64_t*)(Wo + (size_t)t1 * 512 + lane * 8);
    float s0 = 0.f, s1 = 0.f;
    for (int j = 0; j < 8; j++) {
        float fv = fp8_val((int)((fa >> (8 * j)) & 0xFF));
        s0 += fv * fp8_val((int)((wa >> (8 * j)) & 0xFF));
        s1 += fv * fp8_val((int)((wb >> (8 * j)) & 0xFF));
    }
    for (int off = 32; off >= 1; off >>= 1) {
        s0 += __shfl_down(s0, off);
        s1 += __shfl_down(s1, off);
    }
    if (lane == 0) {
        tlog[i * 2 + 0] = s0 * (1.f / 512.f) + bo[t0];
        tlog[i * 2 + 1] = s1 * (1.f / 512.f) + bo[t1];
    }
}

// lse = log(sum of chunk partials) + loss; 16 blocks x 256 rows, atomicAdd
__global__ void k_final(const float* __restrict__ ps,
        const float* __restrict__ tlog, const int* __restrict__ tags,
        const float* __restrict__ dp, float* __restrict__ out) {
    __shared__ float red[256];
    int i = blockIdx.x * 256 + threadIdx.x;
    float S = 0.f;
    for (int j = 0; j < NPART; j++) S += ps[i * NPART + j];
    float lse = logf(S);
    float num = 0.f, den = 0.f;
    for (int k = 0; k < 2; k++) {
        int tg = tags[(i & 2047) * 2 + k];
        float r = 1.0f - dp[tg];
        num += r * (lse - tlog[i * 2 + k]);
        den += r;
    }
    red[threadIdx.x] = num / den;
    __syncthreads();
    for (int s = 128; s > 0; s >>= 1) {
        if (threadIdx.x < s) red[threadIdx.x] += red[threadIdx.x + s];
        __syncthreads();
    }
    if (threadIdx.x == 0) atomicAdd(out, red[0] / (4096.0f + 1e-5f));
}

extern "C" void kernel_launch(void* const* d_in, const int* in_sizes, int n_in,
                              void* d_out, int out_size, void* d_ws, size_t ws_size,
                              hipStream_t stream) {
    const float* hidden = (const float*)d_in[0];
    const float* Wc     = (const float*)d_in[1];
    const float* bc     = (const float*)d_in[2];
    const float* Wp     = (const float*)d_in[3];
    const float* bp     = (const float*)d_in[4];
    const float* Wo     = (const float*)d_in[5];
    const float* bo     = (const float*)d_in[6];
    const float* dp     = (const float*)d_in[7];
    const int* begins   = (const int*)d_in[8];
    const int* ends     = (const int*)d_in[9];
    const int* bids     = (const int*)d_in[10];
    const int* tags     = (const int*)d_in[11];
    float* out = (float*)d_out;

    // workspace carve (all 16B-aligned)
    u8*  Wo8     = (u8*)d_ws;                          // 16,384,000 B (fp8 x32)
    u16* Wc_b    = (u16*)((char*)d_ws + 16384000);     // 512*1024 bf16
    u16* Wp_b    = Wc_b + 524288;
    u16* ctx_b   = Wp_b + 524288;                      // 2048*1024 bf16
    u16* phr_b   = ctx_b + 2097152;
    u8*  feats8  = (u8*)(phr_b + 2097152);             // 4096*512 fp8 x16
    // ps/tlog alias the ctx region (dead after k_feats; in-stream order safe)
    float* ps    = (float*)ctx_b;                      // 4096*32*4 = 512 KB
    float* tlog  = ps + NROWS * NPART;                 // 8192

    k_convert8<<<2048, 256, 0, stream>>>(Wo, Wo8, 16384000);
    k_prep<<<2304, 256, 0, stream>>>(Wc, Wp, hidden, begins, ends, bids,
                                     Wc_b, Wp_b, ctx_b, phr_b);
    k_feats<<<dim3(32, 8, 2), 256, 0, stream>>>(ctx_b, phr_b, Wc_b, Wp_b, bc, bp, feats8);
    k_lse<<<dim3(32, NSC), 256, 0, stream>>>(feats8, Wo8, bo, ps);
    k_taglog<<<1024, 256, 0, stream>>>(feats8, Wo8, bo, tags, tlog);
    hipMemsetAsync(d_out, 0, sizeof(float), stream);
    k_final<<<16, 256, 0, stream>>>(ps, tlog, tags, dp, out);
}